// Round 1
// baseline (928.019 us; speedup 1.0000x reference)
//
#include <hip/hip_runtime.h>
#include <stdint.h>

typedef unsigned long long u64;
typedef unsigned short u16;

// ---------------- sizes ----------------
// x: [4096,12,12,15]  conv1(pad1)->[B,48,12,15]  pool->[B,48,11,14]
// conv2(pad0)->[B,48,9,12]  conv3(pad0)->[B,48,7,10]  pool->[B,48,6,9]
// fc: [B,2592] @ [5,2592]^T

#define NB 4096

// ---------------- workspace layout (bytes) ----------------
#define WS_STATS   0          // long long[288]: sum1,sq1,sum2,sq2,sum3,sq3 (48 each)
#define WS_W1P     4096       // u16[432]
#define WS_W2P     8192       // u64[432]
#define WS_W3P     12288      // u64[432]
#define WS_WFCP    16384      // u64[205]
#define WS_R2      20480      // A1 u16[B*180] / A2 u64[B*154] / A3 u64[B*108] / FBB u64[B*41]
#define WS_R1      5111808    // pooled1 s8[B*7392] / c2 s16[B*5184] / pooled3 s16[B*2592]

// ---------------- d_out offsets (floats) ----------------
#define OUT_OFF 0
#define XB1_OFF 20480
#define XB2_OFF 8867840
#define XB3_OFF 39145472
#define FB_OFF  60379136

__device__ __forceinline__ float fsign(float v) {
    return (v > 0.0f) ? 1.0f : ((v < 0.0f) ? -1.0f : 0.0f);
}

// ---- weight binarize+pack, stats zero ----
__global__ __launch_bounds__(512)
void kw_pack(const float* __restrict__ w1, const float* __restrict__ w2,
             const float* __restrict__ w3, const float* __restrict__ wfc,
             char* __restrict__ ws) {
    int t = threadIdx.x;
    long long* stats = (long long*)(ws + WS_STATS);
    if (t < 288) stats[t] = 0;
    if (t < 432) {
        int oc = t / 9, p = t % 9;
        u16 m1 = 0;
        for (int c = 0; c < 12; ++c)
            if (w1[oc*108 + c*9 + p] > 0.0f) m1 |= (u16)(1u << c);
        ((u16*)(ws + WS_W1P))[t] = m1;
        u64 m2 = 0, m3 = 0;
        for (int c = 0; c < 48; ++c) {
            if (w2[oc*432 + c*9 + p] > 0.0f) m2 |= (1ull << c);
            if (w3[oc*432 + c*9 + p] > 0.0f) m3 |= (1ull << c);
        }
        ((u64*)(ws + WS_W2P))[t] = m2;
        ((u64*)(ws + WS_W3P))[t] = m3;
    }
    if (t < 205) {
        int o = t / 41, j = t % 41;
        u64 m = 0;
        for (int l = 0; l < 64; ++l) {
            int k = j*64 + l;
            if (k < 2592 && wfc[o*2592 + k] > 0.0f) m |= (1ull << l);
        }
        ((u64*)(ws + WS_WFCP))[t] = m;
    }
}

// ---- binarize x -> xb1 floats + A1 bitmasks ----
__global__ __launch_bounds__(256)
void k0_binx(const float* __restrict__ x, float* __restrict__ dout,
             char* __restrict__ ws) {
    int id = blockIdx.x*256 + threadIdx.x;   // b*180 + s, 737280 total
    int b = id / 180, s = id % 180;
    u16 m = 0;
    #pragma unroll
    for (int c = 0; c < 12; ++c) {
        float v = x[b*2160 + c*180 + s];
        dout[XB1_OFF + b*2160 + c*180 + s] = fsign(v);
        if (v > 0.0f) m |= (u16)(1u << c);
    }
    ((u16*)(ws + WS_R2))[id] = m;
}

// ---- conv1 (pad1) + maxpool 2x2/s1 + BN1 stats ----
__global__ __launch_bounds__(256)
void k1_conv1(char* __restrict__ ws) {
    __shared__ u16 As[180];
    __shared__ u16 Wsh[432];
    __shared__ signed char cmap[8640];      // [48][12][15]
    __shared__ int ssum[48], ssq[48];
    int t = threadIdx.x, b = blockIdx.x;
    const u16* A1 = (const u16*)(ws + WS_R2);
    const u16* W1p = (const u16*)(ws + WS_W1P);
    if (t < 180) As[t] = A1[b*180 + t];
    for (int i = t; i < 432; i += 256) Wsh[i] = W1p[i];
    if (t < 48) { ssum[t] = 0; ssq[t] = 0; }
    __syncthreads();
    for (int i = t; i < 8640; i += 256) {
        int oc = i / 180, s = i % 180, y = s / 15, xx = s % 15;
        int acc = 0, valid = 0;
        #pragma unroll
        for (int ky = 0; ky < 3; ++ky) {
            int yy = y + ky - 1;
            if (yy < 0 || yy >= 12) continue;
            #pragma unroll
            for (int kx = 0; kx < 3; ++kx) {
                int xc = xx + kx - 1;
                if (xc < 0 || xc >= 15) continue;
                acc += __popc((unsigned)(As[yy*15 + xc] ^ Wsh[oc*9 + ky*3 + kx]));
                valid += 12;
            }
        }
        cmap[i] = (signed char)(valid - 2*acc);
    }
    __syncthreads();
    signed char* pooled1 = (signed char*)(ws + WS_R1);
    for (int i = t; i < 7392; i += 256) {  // [48][11][14]
        int c = i / 154, s = i % 154, py = s / 14, px = s % 14;
        int base = c*180 + py*15 + px;
        int m0 = cmap[base], m1 = cmap[base+1], m2 = cmap[base+15], m3 = cmap[base+16];
        int mx = max(max(m0, m1), max(m2, m3));
        pooled1[b*7392 + i] = (signed char)mx;
        atomicAdd(&ssum[c], mx);
        atomicAdd(&ssq[c], mx*mx);
    }
    __syncthreads();
    if (t < 48) {
        u64* st = (u64*)(ws + WS_STATS);
        atomicAdd(&st[t],      (u64)(long long)ssum[t]);
        atomicAdd(&st[48 + t], (u64)(long long)ssq[t]);
    }
}

// ---- BN1 sign -> xb2 floats + A2 masks ----
__global__ __launch_bounds__(256)
void k3_bin2(const float* __restrict__ g1, const float* __restrict__ b1,
             float* __restrict__ dout, char* __restrict__ ws) {
    __shared__ float sc[48], sh[48];
    __shared__ signed char sm[7392];
    int t = threadIdx.x, b = blockIdx.x;
    if (t < 48) {
        const long long* st = (const long long*)(ws + WS_STATS);
        double N = 630784.0;   // 4096*11*14
        double mean = (double)st[t] / N;
        double var  = (double)st[48+t] / N - mean*mean;
        double scale = (double)g1[t] / sqrt(var + 1e-5);
        sc[t] = (float)scale;
        sh[t] = (float)((double)b1[t] - mean*scale);
    }
    __syncthreads();
    const signed char* pooled1 = (const signed char*)(ws + WS_R1);
    for (int i = t; i < 7392; i += 256) {
        signed char v = pooled1[b*7392 + i];
        sm[i] = v;
        int c = i / 154;
        dout[XB2_OFF + b*7392 + i] = fsign(sc[c]*(float)v + sh[c]);
    }
    __syncthreads();
    if (t < 154) {
        u64 m = 0;
        #pragma unroll
        for (int c = 0; c < 48; ++c)
            if (sc[c]*(float)sm[c*154 + t] + sh[c] > 0.0f) m |= (1ull << c);
        ((u64*)(ws + WS_R2))[b*154 + t] = m;
    }
}

// ---- conv2 (pad0) + BN2 stats ----
__global__ __launch_bounds__(256)
void k4_conv2(char* __restrict__ ws) {
    __shared__ u64 As[154];
    __shared__ u64 Wsh[432];
    __shared__ int ssum[48], ssq[48];
    int t = threadIdx.x, b = blockIdx.x;
    const u64* A2 = (const u64*)(ws + WS_R2);
    const u64* W2p = (const u64*)(ws + WS_W2P);
    if (t < 154) As[t] = A2[b*154 + t];
    for (int i = t; i < 432; i += 256) Wsh[i] = W2p[i];
    if (t < 48) { ssum[t] = 0; ssq[t] = 0; }
    __syncthreads();
    short* c2 = (short*)(ws + WS_R1);
    for (int i = t; i < 5184; i += 256) {  // [48][9][12]
        int oc = i / 108, s = i % 108, oy = s / 12, ox = s % 12;
        int acc = 0;
        #pragma unroll
        for (int ky = 0; ky < 3; ++ky)
            #pragma unroll
            for (int kx = 0; kx < 3; ++kx)
                acc += __popcll(As[(oy+ky)*14 + ox+kx] ^ Wsh[oc*9 + ky*3 + kx]);
        int v = 432 - 2*acc;
        c2[b*5184 + i] = (short)v;
        atomicAdd(&ssum[oc], v);
        atomicAdd(&ssq[oc], v*v);
    }
    __syncthreads();
    if (t < 48) {
        u64* st = (u64*)(ws + WS_STATS);
        atomicAdd(&st[96 + t],  (u64)(long long)ssum[t]);
        atomicAdd(&st[144 + t], (u64)(long long)ssq[t]);
    }
}

// ---- BN2 sign -> xb3 floats + A3 masks ----
__global__ __launch_bounds__(256)
void k6_bin3(const float* __restrict__ g2, const float* __restrict__ b2,
             float* __restrict__ dout, char* __restrict__ ws) {
    __shared__ float sc[48], sh[48];
    __shared__ short sm[5184];
    int t = threadIdx.x, b = blockIdx.x;
    if (t < 48) {
        const long long* st = (const long long*)(ws + WS_STATS);
        double N = 442368.0;   // 4096*9*12
        double mean = (double)st[96+t] / N;
        double var  = (double)st[144+t] / N - mean*mean;
        double scale = (double)g2[t] / sqrt(var + 1e-5);
        sc[t] = (float)scale;
        sh[t] = (float)((double)b2[t] - mean*scale);
    }
    __syncthreads();
    const short* c2 = (const short*)(ws + WS_R1);
    for (int i = t; i < 5184; i += 256) {
        short v = c2[b*5184 + i];
        sm[i] = v;
        int c = i / 108;
        dout[XB3_OFF + b*5184 + i] = fsign(sc[c]*(float)v + sh[c]);
    }
    __syncthreads();
    if (t < 108) {
        u64 m = 0;
        #pragma unroll
        for (int c = 0; c < 48; ++c)
            if (sc[c]*(float)sm[c*108 + t] + sh[c] > 0.0f) m |= (1ull << c);
        ((u64*)(ws + WS_R2))[b*108 + t] = m;
    }
}

// ---- conv3 (pad0) + maxpool 2x2/s1 + BN3 stats ----
__global__ __launch_bounds__(256)
void k7_conv3(char* __restrict__ ws) {
    __shared__ u64 As[108];
    __shared__ u64 Wsh[432];
    __shared__ short cmap[3360];   // [48][7][10]
    __shared__ int ssum[48], ssq[48];
    int t = threadIdx.x, b = blockIdx.x;
    const u64* A3 = (const u64*)(ws + WS_R2);
    const u64* W3p = (const u64*)(ws + WS_W3P);
    if (t < 108) As[t] = A3[b*108 + t];
    for (int i = t; i < 432; i += 256) Wsh[i] = W3p[i];
    if (t < 48) { ssum[t] = 0; ssq[t] = 0; }
    __syncthreads();
    for (int i = t; i < 3360; i += 256) {
        int oc = i / 70, s = i % 70, oy = s / 10, ox = s % 10;
        int acc = 0;
        #pragma unroll
        for (int ky = 0; ky < 3; ++ky)
            #pragma unroll
            for (int kx = 0; kx < 3; ++kx)
                acc += __popcll(As[(oy+ky)*12 + ox+kx] ^ Wsh[oc*9 + ky*3 + kx]);
        cmap[i] = (short)(432 - 2*acc);
    }
    __syncthreads();
    short* pooled3 = (short*)(ws + WS_R1);
    for (int i = t; i < 2592; i += 256) {  // [48][6][9]
        int c = i / 54, s = i % 54, py = s / 9, px = s % 9;
        int base = c*70 + py*10 + px;
        int mx = max(max((int)cmap[base],    (int)cmap[base+1]),
                     max((int)cmap[base+10], (int)cmap[base+11]));
        pooled3[b*2592 + i] = (short)mx;
        atomicAdd(&ssum[c], mx);
        atomicAdd(&ssq[c], mx*mx);
    }
    __syncthreads();
    if (t < 48) {
        u64* st = (u64*)(ws + WS_STATS);
        atomicAdd(&st[192 + t], (u64)(long long)ssum[t]);
        atomicAdd(&st[240 + t], (u64)(long long)ssq[t]);
    }
}

// ---- BN3 sign -> fb floats + packed fb bits (ballot) ----
__global__ __launch_bounds__(256)
void k9_fb(const float* __restrict__ g3, const float* __restrict__ b3,
           float* __restrict__ dout, char* __restrict__ ws) {
    __shared__ float sc[48], sh[48];
    int t = threadIdx.x, b = blockIdx.x;
    if (t < 48) {
        const long long* st = (const long long*)(ws + WS_STATS);
        double N = 221184.0;   // 4096*6*9
        double mean = (double)st[192+t] / N;
        double var  = (double)st[240+t] / N - mean*mean;
        double scale = (double)g3[t] / sqrt(var + 1e-5);
        sc[t] = (float)scale;
        sh[t] = (float)((double)b3[t] - mean*scale);
    }
    __syncthreads();
    const short* pooled3 = (const short*)(ws + WS_R1);
    u64* fbb = (u64*)(ws + WS_R2);
    int wave = t >> 6, lane = t & 63;
    for (int word = wave; word < 41; word += 4) {
        int k = word*64 + lane;
        bool pred = false;
        if (k < 2592) {
            int c = k / 54;
            float bn = sc[c]*(float)pooled3[b*2592 + k] + sh[c];
            dout[FB_OFF + b*2592 + k] = fsign(bn);
            pred = bn > 0.0f;
        }
        u64 m = __ballot(pred);
        if (lane == 0) fbb[b*41 + word] = m;
    }
}

// ---- fc: out = fb @ wfc_b^T via popcount ----
__global__ __launch_bounds__(256)
void k10_fc(float* __restrict__ dout, char* __restrict__ ws) {
    __shared__ u64 Wf[205];
    int t = threadIdx.x;
    const u64* WFCp = (const u64*)(ws + WS_WFCP);
    if (t < 205) Wf[t] = WFCp[t];
    __syncthreads();
    int id = blockIdx.x*256 + t;  // 20480 = 4096*5
    int b = id / 5, o = id % 5;
    const u64* fbb = (const u64*)(ws + WS_R2);
    int acc = 0;
    #pragma unroll 8
    for (int j = 0; j < 41; ++j)
        acc += __popcll(fbb[b*41 + j] ^ Wf[o*41 + j]);
    dout[OUT_OFF + id] = (float)(2592 - 2*acc);
}

extern "C" void kernel_launch(void* const* d_in, const int* in_sizes, int n_in,
                              void* d_out, int out_size, void* d_ws, size_t ws_size,
                              hipStream_t stream) {
    const float* x   = (const float*)d_in[0];
    const float* w1  = (const float*)d_in[1];
    const float* g1  = (const float*)d_in[2];
    const float* b1  = (const float*)d_in[3];
    const float* w2  = (const float*)d_in[4];
    const float* g2  = (const float*)d_in[5];
    const float* b2  = (const float*)d_in[6];
    const float* w3  = (const float*)d_in[7];
    const float* g3  = (const float*)d_in[8];
    const float* b3  = (const float*)d_in[9];
    const float* wfc = (const float*)d_in[10];
    float* out = (float*)d_out;
    char* ws = (char*)d_ws;

    hipLaunchKernelGGL(kw_pack, dim3(1),    dim3(512), 0, stream, w1, w2, w3, wfc, ws);
    hipLaunchKernelGGL(k0_binx, dim3(2880), dim3(256), 0, stream, x, out, ws);
    hipLaunchKernelGGL(k1_conv1,dim3(NB),   dim3(256), 0, stream, ws);
    hipLaunchKernelGGL(k3_bin2, dim3(NB),   dim3(256), 0, stream, g1, b1, out, ws);
    hipLaunchKernelGGL(k4_conv2,dim3(NB),   dim3(256), 0, stream, ws);
    hipLaunchKernelGGL(k6_bin3, dim3(NB),   dim3(256), 0, stream, g2, b2, out, ws);
    hipLaunchKernelGGL(k7_conv3,dim3(NB),   dim3(256), 0, stream, ws);
    hipLaunchKernelGGL(k9_fb,   dim3(NB),   dim3(256), 0, stream, g3, b3, out, ws);
    hipLaunchKernelGGL(k10_fc,  dim3(80),   dim3(256), 0, stream, out, ws);
}

// Round 2
// 734.605 us; speedup vs baseline: 1.2633x; 1.2633x over previous
//
#include <hip/hip_runtime.h>
#include <stdint.h>

typedef unsigned long long u64;
typedef unsigned short u16;

// ---------------- sizes ----------------
// x: [4096,12,12,15]  conv1(pad1)->[B,48,12,15]  pool->[B,48,11,14]
// conv2(pad0)->[B,48,9,12]  conv3(pad0)->[B,48,7,10]  pool->[B,48,6,9]
// fc: [B,2592] @ [5,2592]^T

#define NB 4096

// ---------------- workspace layout (bytes) ----------------
// stats: long long[288][8 slots]: idx = stat*8 + slot
//   stat: sum1(c), 48+sq1(c), 96+sum2, 144+sq2, 192+sum3, 240+sq3
#define WS_STATS 0          // 288*8*8 = 18432 B
#define WS_W1P   20480      // u16[432]
#define WS_W2P   24576      // u64[432]
#define WS_W3P   28672      // u64[432]
#define WS_WFCP  32768      // u64[205]
#define WS_A1    40960      // u16[4096*180]  (reused later as A2 u64[4096*154] = 5,046,272 B)
#define WS_P1    5111808    // pooled1 s8[4096*7392] (reused later as pooled3 s16[4096*2592])

// ---------------- d_out offsets (floats) ----------------
#define OUT_OFF 0
#define XB1_OFF 20480
#define XB2_OFF 8867840
#define XB3_OFF 39145472
#define FB_OFF  60379136

__device__ __forceinline__ float fsign(float v) {
    return (v > 0.0f) ? 1.0f : ((v < 0.0f) ? -1.0f : 0.0f);
}

// ---- weight binarize+pack, stats zero ----
__global__ __launch_bounds__(512)
void kw_pack(const float* __restrict__ w1, const float* __restrict__ w2,
             const float* __restrict__ w3, const float* __restrict__ wfc,
             char* __restrict__ ws) {
    int t = threadIdx.x;
    long long* stats = (long long*)(ws + WS_STATS);
    for (int i = t; i < 2304; i += 512) stats[i] = 0;
    if (t < 432) {
        int oc = t / 9, p = t % 9;
        u16 m1 = 0;
        for (int c = 0; c < 12; ++c)
            if (w1[oc*108 + c*9 + p] > 0.0f) m1 |= (u16)(1u << c);
        ((u16*)(ws + WS_W1P))[t] = m1;
        u64 m2 = 0, m3 = 0;
        for (int c = 0; c < 48; ++c) {
            if (w2[oc*432 + c*9 + p] > 0.0f) m2 |= (1ull << c);
            if (w3[oc*432 + c*9 + p] > 0.0f) m3 |= (1ull << c);
        }
        ((u64*)(ws + WS_W2P))[t] = m2;
        ((u64*)(ws + WS_W3P))[t] = m3;
    }
    if (t < 205) {
        int o = t / 41, j = t % 41;
        u64 m = 0;
        for (int l = 0; l < 64; ++l) {
            int k = j*64 + l;
            if (k < 2592 && wfc[o*2592 + k] > 0.0f) m |= (1ull << l);
        }
        ((u64*)(ws + WS_WFCP))[t] = m;
    }
}

// ---- binarize x -> xb1 floats (float4) + A1 bitmasks ----
__global__ __launch_bounds__(256)
void k0_binx(const float* __restrict__ x, float* __restrict__ dout,
             char* __restrict__ ws) {
    int id = blockIdx.x*256 + threadIdx.x;   // 184320 = 4096*45
    int b = id / 45, s4 = id % 45;
    const float4* xp = (const float4*)(x + b*2160);
    float4* op = (float4*)(dout + XB1_OFF + (size_t)b*2160);
    u16 m0 = 0, m1 = 0, m2 = 0, m3 = 0;
    #pragma unroll
    for (int c = 0; c < 12; ++c) {
        float4 v = xp[c*45 + s4];
        float4 o;
        o.x = fsign(v.x); o.y = fsign(v.y); o.z = fsign(v.z); o.w = fsign(v.w);
        op[c*45 + s4] = o;
        u16 bit = (u16)(1u << c);
        if (v.x > 0.0f) m0 |= bit;
        if (v.y > 0.0f) m1 |= bit;
        if (v.z > 0.0f) m2 |= bit;
        if (v.w > 0.0f) m3 |= bit;
    }
    ushort4 mm; mm.x = m0; mm.y = m1; mm.z = m2; mm.w = m3;
    *((ushort4*)((u16*)(ws + WS_A1) + b*180 + s4*4)) = mm;
}

// ---- conv1 (pad1) + maxpool 2x2/s1 + BN1 stats (wave-reduced) ----
__global__ __launch_bounds__(256)
void k1_conv1(char* __restrict__ ws) {
    __shared__ u16 As[180];
    __shared__ u16 Wsh[432];
    __shared__ int cmap_i[2160];   // signed char [48][12][15] packed
    __shared__ int pl_i[1848];     // signed char [48][11][14] packed
    signed char* cmap = (signed char*)cmap_i;
    signed char* pl = (signed char*)pl_i;
    int t = threadIdx.x, b = blockIdx.x;
    const u16* A1 = (const u16*)(ws + WS_A1);
    const u16* W1p = (const u16*)(ws + WS_W1P);
    if (t < 180) As[t] = A1[b*180 + t];
    for (int i = t; i < 432; i += 256) Wsh[i] = W1p[i];
    __syncthreads();
    for (int i4 = t; i4 < 2160; i4 += 256) {
        int r = 0;
        #pragma unroll
        for (int u = 0; u < 4; ++u) {
            int i = i4*4 + u;
            int oc = i / 180, s = i % 180, y = s / 15, xx = s % 15;
            int acc = 0, valid = 0;
            #pragma unroll
            for (int ky = 0; ky < 3; ++ky) {
                int yy = y + ky - 1;
                if (yy < 0 || yy >= 12) continue;
                #pragma unroll
                for (int kx = 0; kx < 3; ++kx) {
                    int xc = xx + kx - 1;
                    if (xc < 0 || xc >= 15) continue;
                    acc += __popc((unsigned)(As[yy*15 + xc] ^ Wsh[oc*9 + ky*3 + kx]));
                    valid += 12;
                }
            }
            r |= ((valid - 2*acc) & 0xff) << (8*u);
        }
        cmap_i[i4] = r;
    }
    __syncthreads();
    int* gp = (int*)(ws + WS_P1 + (size_t)b*7392);
    for (int i4 = t; i4 < 1848; i4 += 256) {
        int r = 0;
        #pragma unroll
        for (int u = 0; u < 4; ++u) {
            int i = i4*4 + u;
            int c = i / 154, s = i % 154, py = s / 14, px = s % 14;
            int base = c*180 + py*15 + px;
            int mx = max(max((int)cmap[base],    (int)cmap[base+1]),
                         max((int)cmap[base+15], (int)cmap[base+16]));
            r |= (mx & 0xff) << (8*u);
        }
        pl_i[i4] = r;
        gp[i4] = r;
    }
    __syncthreads();
    int wv = t >> 6, ln = t & 63, slot = b & 7;
    u64* st = (u64*)(ws + WS_STATS);
    for (int c = wv; c < 48; c += 4) {
        int sum = 0, sq = 0;
        for (int s = ln; s < 154; s += 64) {
            int v = pl[c*154 + s];
            sum += v; sq += v*v;
        }
        #pragma unroll
        for (int off = 32; off >= 1; off >>= 1) {
            sum += __shfl_down(sum, off);
            sq  += __shfl_down(sq, off);
        }
        if (ln == 0) {
            atomicAdd(&st[(c)*8 + slot],      (u64)(long long)sum);
            atomicAdd(&st[(48 + c)*8 + slot], (u64)(long long)sq);
        }
    }
}

// ---- BN1 apply -> xb2 + A2 masks + conv2 + BN2 stats ----
__global__ __launch_bounds__(256)
void kA_bn1conv2(const float* __restrict__ g1, const float* __restrict__ b1,
                 float* __restrict__ dout, char* __restrict__ ws) {
    __shared__ float sc[48], sh[48];
    __shared__ int sm_i[1848];     // pooled1 s8 [48][154]
    __shared__ u64 As[154];
    __shared__ u64 Wsh[432];
    __shared__ short c2[5184];
    signed char* sm = (signed char*)sm_i;
    int t = threadIdx.x, b = blockIdx.x;
    const int* gp = (const int*)(ws + WS_P1 + (size_t)b*7392);
    for (int i4 = t; i4 < 1848; i4 += 256) sm_i[i4] = gp[i4];
    const u64* W2p = (const u64*)(ws + WS_W2P);
    for (int i = t; i < 432; i += 256) Wsh[i] = W2p[i];
    if (t < 48) {
        const long long* st = (const long long*)(ws + WS_STATS);
        long long s = 0, q = 0;
        #pragma unroll
        for (int k = 0; k < 8; ++k) { s += st[t*8 + k]; q += st[(48 + t)*8 + k]; }
        double N = 630784.0;   // 4096*11*14
        double mean = (double)s / N;
        double var  = (double)q / N - mean*mean;
        double scale = (double)g1[t] / sqrt(var + 1e-5);
        sc[t] = (float)scale;
        sh[t] = (float)((double)b1[t] - mean*scale);
    }
    __syncthreads();
    float4* xo = (float4*)(dout + XB2_OFF + (size_t)b*7392);
    for (int i4 = t; i4 < 1848; i4 += 256) {
        int pv = sm_i[i4];
        int i = i4*4;
        float4 o;
        int c0 = i/154, c1 = (i+1)/154, c2i = (i+2)/154, c3 = (i+3)/154;
        o.x = fsign(sc[c0]*(float)(signed char)(pv)       + sh[c0]);
        o.y = fsign(sc[c1]*(float)(signed char)(pv >> 8)  + sh[c1]);
        o.z = fsign(sc[c2i]*(float)(signed char)(pv >> 16) + sh[c2i]);
        o.w = fsign(sc[c3]*(float)(signed char)(pv >> 24) + sh[c3]);
        xo[i4] = o;
    }
    if (t < 154) {
        u64 m = 0;
        #pragma unroll
        for (int c = 0; c < 48; ++c)
            if (sc[c]*(float)sm[c*154 + t] + sh[c] > 0.0f) m |= (1ull << c);
        As[t] = m;
        ((u64*)(ws + WS_A1))[(size_t)b*154 + t] = m;
    }
    __syncthreads();
    for (int i = t; i < 5184; i += 256) {  // [48][9][12]
        int oc = i / 108, s = i % 108, oy = s / 12, ox = s % 12;
        int acc = 0;
        #pragma unroll
        for (int ky = 0; ky < 3; ++ky)
            #pragma unroll
            for (int kx = 0; kx < 3; ++kx)
                acc += __popcll(As[(oy+ky)*14 + ox+kx] ^ Wsh[oc*9 + ky*3 + kx]);
        c2[i] = (short)(432 - 2*acc);
    }
    __syncthreads();
    int wv = t >> 6, ln = t & 63, slot = b & 7;
    u64* st = (u64*)(ws + WS_STATS);
    for (int c = wv; c < 48; c += 4) {
        int sum = 0, sq = 0;
        for (int s = ln; s < 108; s += 64) {
            int v = c2[c*108 + s];
            sum += v; sq += v*v;
        }
        #pragma unroll
        for (int off = 32; off >= 1; off >>= 1) {
            sum += __shfl_down(sum, off);
            sq  += __shfl_down(sq, off);
        }
        if (ln == 0) {
            atomicAdd(&st[(96 + c)*8 + slot],  (u64)(long long)sum);
            atomicAdd(&st[(144 + c)*8 + slot], (u64)(long long)sq);
        }
    }
}

// ---- conv2 recompute + BN2 apply -> xb3 + conv3 + pool + BN3 stats ----
__global__ __launch_bounds__(256)
void kB_bn2conv3(const float* __restrict__ g2, const float* __restrict__ b2,
                 float* __restrict__ dout, char* __restrict__ ws) {
    __shared__ float sc[48], sh[48];
    __shared__ u64 As[154];
    __shared__ u64 W2s[432];
    __shared__ u64 W3s[432];
    __shared__ short c2[5184];
    __shared__ u64 A3[108];
    __shared__ short cm[3360];   // [48][7][10]
    __shared__ short pl[2592];   // [48][6][9]
    int t = threadIdx.x, b = blockIdx.x;
    if (t < 154) As[t] = ((const u64*)(ws + WS_A1))[(size_t)b*154 + t];
    const u64* W2p = (const u64*)(ws + WS_W2P);
    const u64* W3p = (const u64*)(ws + WS_W3P);
    for (int i = t; i < 432; i += 256) { W2s[i] = W2p[i]; W3s[i] = W3p[i]; }
    if (t < 48) {
        const long long* st = (const long long*)(ws + WS_STATS);
        long long s = 0, q = 0;
        #pragma unroll
        for (int k = 0; k < 8; ++k) { s += st[(96 + t)*8 + k]; q += st[(144 + t)*8 + k]; }
        double N = 442368.0;   // 4096*9*12
        double mean = (double)s / N;
        double var  = (double)q / N - mean*mean;
        double scale = (double)g2[t] / sqrt(var + 1e-5);
        sc[t] = (float)scale;
        sh[t] = (float)((double)b2[t] - mean*scale);
    }
    __syncthreads();
    for (int i = t; i < 5184; i += 256) {
        int oc = i / 108, s = i % 108, oy = s / 12, ox = s % 12;
        int acc = 0;
        #pragma unroll
        for (int ky = 0; ky < 3; ++ky)
            #pragma unroll
            for (int kx = 0; kx < 3; ++kx)
                acc += __popcll(As[(oy+ky)*14 + ox+kx] ^ W2s[oc*9 + ky*3 + kx]);
        c2[i] = (short)(432 - 2*acc);
    }
    __syncthreads();
    float4* xo = (float4*)(dout + XB3_OFF + (size_t)b*5184);
    for (int i4 = t; i4 < 1296; i4 += 256) {
        int i = i4*4;
        float4 o;
        int c0 = i/108, c1 = (i+1)/108, c2i = (i+2)/108, c3 = (i+3)/108;
        o.x = fsign(sc[c0]*(float)c2[i]   + sh[c0]);
        o.y = fsign(sc[c1]*(float)c2[i+1] + sh[c1]);
        o.z = fsign(sc[c2i]*(float)c2[i+2] + sh[c2i]);
        o.w = fsign(sc[c3]*(float)c2[i+3] + sh[c3]);
        xo[i4] = o;
    }
    if (t < 108) {
        u64 m = 0;
        #pragma unroll
        for (int c = 0; c < 48; ++c)
            if (sc[c]*(float)c2[c*108 + t] + sh[c] > 0.0f) m |= (1ull << c);
        A3[t] = m;
    }
    __syncthreads();
    for (int i = t; i < 3360; i += 256) {
        int oc = i / 70, s = i % 70, oy = s / 10, ox = s % 10;
        int acc = 0;
        #pragma unroll
        for (int ky = 0; ky < 3; ++ky)
            #pragma unroll
            for (int kx = 0; kx < 3; ++kx)
                acc += __popcll(A3[(oy+ky)*12 + ox+kx] ^ W3s[oc*9 + ky*3 + kx]);
        cm[i] = (short)(432 - 2*acc);
    }
    __syncthreads();
    short* p3g = (short*)(ws + WS_P1) + (size_t)b*2592;
    for (int i = t; i < 2592; i += 256) {
        int c = i / 54, s = i % 54, py = s / 9, px = s % 9;
        int base = c*70 + py*10 + px;
        int mx = max(max((int)cm[base],    (int)cm[base+1]),
                     max((int)cm[base+10], (int)cm[base+11]));
        pl[i] = (short)mx;
        p3g[i] = (short)mx;
    }
    __syncthreads();
    int wv = t >> 6, ln = t & 63, slot = b & 7;
    u64* st = (u64*)(ws + WS_STATS);
    for (int c = wv; c < 48; c += 4) {
        int sum = 0, sq = 0;
        for (int s = ln; s < 54; s += 64) {
            int v = pl[c*54 + s];
            sum += v; sq += v*v;
        }
        #pragma unroll
        for (int off = 32; off >= 1; off >>= 1) {
            sum += __shfl_down(sum, off);
            sq  += __shfl_down(sq, off);
        }
        if (ln == 0) {
            atomicAdd(&st[(192 + c)*8 + slot], (u64)(long long)sum);
            atomicAdd(&st[(240 + c)*8 + slot], (u64)(long long)sq);
        }
    }
}

// ---- BN3 apply -> fb + FC ----
__global__ __launch_bounds__(256)
void kC_fbfc(const float* __restrict__ g3, const float* __restrict__ b3,
             float* __restrict__ dout, char* __restrict__ ws) {
    __shared__ float sc[48], sh[48];
    __shared__ short4 sm4[648];
    __shared__ unsigned char nib[648];
    __shared__ u64 fbb[41];
    short* sm = (short*)sm4;
    int t = threadIdx.x, b = blockIdx.x;
    const short4* p3 = (const short4*)((const short*)(ws + WS_P1) + (size_t)b*2592);
    for (int i4 = t; i4 < 648; i4 += 256) sm4[i4] = p3[i4];
    if (t < 48) {
        const long long* st = (const long long*)(ws + WS_STATS);
        long long s = 0, q = 0;
        #pragma unroll
        for (int k = 0; k < 8; ++k) { s += st[(192 + t)*8 + k]; q += st[(240 + t)*8 + k]; }
        double N = 221184.0;   // 4096*6*9
        double mean = (double)s / N;
        double var  = (double)q / N - mean*mean;
        double scale = (double)g3[t] / sqrt(var + 1e-5);
        sc[t] = (float)scale;
        sh[t] = (float)((double)b3[t] - mean*scale);
    }
    __syncthreads();
    float4* fo = (float4*)(dout + FB_OFF + (size_t)b*2592);
    for (int i4 = t; i4 < 648; i4 += 256) {
        int i = i4*4;
        float4 o;
        unsigned n = 0;
        int c0 = i/54, c1 = (i+1)/54, c2 = (i+2)/54, c3 = (i+3)/54;
        float v0 = sc[c0]*(float)sm[i]   + sh[c0];
        float v1 = sc[c1]*(float)sm[i+1] + sh[c1];
        float v2 = sc[c2]*(float)sm[i+2] + sh[c2];
        float v3 = sc[c3]*(float)sm[i+3] + sh[c3];
        o.x = fsign(v0); o.y = fsign(v1); o.z = fsign(v2); o.w = fsign(v3);
        if (v0 > 0.0f) n |= 1u;
        if (v1 > 0.0f) n |= 2u;
        if (v2 > 0.0f) n |= 4u;
        if (v3 > 0.0f) n |= 8u;
        fo[i4] = o;
        nib[i4] = (unsigned char)n;
    }
    __syncthreads();
    if (t < 41) {
        u64 m = 0;
        #pragma unroll
        for (int k = 0; k < 16; ++k) {
            int j = t*16 + k;
            if (j < 648) m |= ((u64)nib[j]) << (4*k);
        }
        fbb[t] = m;
    }
    __syncthreads();
    if (t < 5) {
        const u64* Wf = (const u64*)(ws + WS_WFCP) + t*41;
        int acc = 0;
        #pragma unroll
        for (int j = 0; j < 41; ++j) acc += __popcll(fbb[j] ^ Wf[j]);
        dout[OUT_OFF + b*5 + t] = (float)(2592 - 2*acc);
    }
}

extern "C" void kernel_launch(void* const* d_in, const int* in_sizes, int n_in,
                              void* d_out, int out_size, void* d_ws, size_t ws_size,
                              hipStream_t stream) {
    const float* x   = (const float*)d_in[0];
    const float* w1  = (const float*)d_in[1];
    const float* g1  = (const float*)d_in[2];
    const float* b1  = (const float*)d_in[3];
    const float* w2  = (const float*)d_in[4];
    const float* g2  = (const float*)d_in[5];
    const float* b2  = (const float*)d_in[6];
    const float* w3  = (const float*)d_in[7];
    const float* g3  = (const float*)d_in[8];
    const float* b3  = (const float*)d_in[9];
    const float* wfc = (const float*)d_in[10];
    float* out = (float*)d_out;
    char* ws = (char*)d_ws;

    hipLaunchKernelGGL(kw_pack,     dim3(1),    dim3(512), 0, stream, w1, w2, w3, wfc, ws);
    hipLaunchKernelGGL(k0_binx,     dim3(720),  dim3(256), 0, stream, x, out, ws);
    hipLaunchKernelGGL(k1_conv1,    dim3(NB),   dim3(256), 0, stream, ws);
    hipLaunchKernelGGL(kA_bn1conv2, dim3(NB),   dim3(256), 0, stream, g1, b1, out, ws);
    hipLaunchKernelGGL(kB_bn2conv3, dim3(NB),   dim3(256), 0, stream, g2, b2, out, ws);
    hipLaunchKernelGGL(kC_fbfc,     dim3(NB),   dim3(256), 0, stream, g3, b3, out, ws);
}